// Round 6
// baseline (501.187 us; speedup 1.0000x reference)
//
#include <hip/hip_runtime.h>

#define NBLK 128
#define BLK  8
#define BB   4
#define SS   4096
#define DD   1024
#define PLANE (BB * SS * DD)          // 16,777,216 floats per output plane
#define APPLY_WGS 4096
#define THREADS (APPLY_WGS * 256)     // 1,048,576 threads
#define NITER (PLANE / 4 / THREADS)   // 4 float4-tiles per thread

typedef float floatx4 __attribute__((ext_vector_type(4)));

// ---------------------------------------------------------------------------
// Kernel 1: Cayley transform. 128 independent 16x16 solves (real-block
// isomorphism of the 8x8 complex system). 16 threads per solve, one row
// each; row kept in registers; pivot row broadcast through LDS.
// ---------------------------------------------------------------------------
__global__ __launch_bounds__(256) void cayley_kernel(
    const float* __restrict__ Ar, const float* __restrict__ Ai,
    float* __restrict__ Ur, float* __restrict__ Ui) {
  __shared__ float piv[16][33];
  const int s = threadIdx.x >> 4;
  const int r = threadIdx.x & 15;
  const int n = blockIdx.x * 16 + s;
  const float* arb = Ar + n * 64;
  const float* aib = Ai + n * 64;

  float row[32];
  if (r < 8) {
    #pragma unroll
    for (int c = 0; c < 8; ++c) {
      float sk = 0.5f * (arb[r * 8 + c] - arb[c * 8 + r]);
      float sy = 0.5f * (aib[r * 8 + c] + aib[c * 8 + r]);
      float d  = (c == r) ? 1.0f : 0.0f;
      row[c]      = d + sk;
      row[8 + c]  = -sy;
      row[16 + c] = d - sk;
      row[24 + c] = sy;
    }
  } else {
    const int rr = r - 8;
    #pragma unroll
    for (int c = 0; c < 8; ++c) {
      float sk = 0.5f * (arb[rr * 8 + c] - arb[c * 8 + rr]);
      float sy = 0.5f * (aib[rr * 8 + c] + aib[c * 8 + rr]);
      float d  = (c == rr) ? 1.0f : 0.0f;
      row[c]      = sy;
      row[8 + c]  = d + sk;
      row[16 + c] = -sy;
      row[24 + c] = d - sk;
    }
  }

  #pragma unroll
  for (int k = 0; k < 16; ++k) {
    if (r == k) {
      float inv = 1.0f / row[k];
      #pragma unroll
      for (int j = 0; j < 32; ++j) { row[j] *= inv; piv[s][j] = row[j]; }
    }
    __syncthreads();
    if (r != k) {
      float f = row[k];
      #pragma unroll
      for (int j = 0; j < 32; ++j) row[j] = fmaf(-f, piv[s][j], row[j]);
    }
    __syncthreads();
  }

  if (r < 8) {
    #pragma unroll
    for (int c = 0; c < 8; ++c) Ur[n * 64 + r * 8 + c] = row[16 + c];
  } else {
    #pragma unroll
    for (int c = 0; c < 8; ++c) Ui[n * 64 + (r - 8) * 8 + c] = row[16 + c];
  }
}

// ---------------------------------------------------------------------------
// Kernel 2 (R6 = R5 + 4x grid): one float4 (= half block, 4 output rows)
// per thread; dense 16B/lane loads; partner half via __shfl_xor(.,1);
// U rows pinned in 32 VGPRs; float4 NT stores.
// R5 lesson: 1024 wgs = exactly 4 wg/CU — THE GRID capped occupancy at 38%
// even though VGPR=64 permits 8 wg/CU. 4096 wgs -> 8 wg/CU resident,
// 32 waves/CU, 2x latency-hiding. __launch_bounds__(256,8) pins VGPR<=64.
// ---------------------------------------------------------------------------
__global__ __launch_bounds__(256, 8) void apply_kernel(
    const float* __restrict__ xr, const float* __restrict__ xi,
    const float* __restrict__ Urg, const float* __restrict__ Uig,
    float* __restrict__ out) {
  const int G = blockIdx.x * 256 + threadIdx.x;   // thread linear id
  const int p = G & 255;         // position within 256-float4 (=1024-elem) tile
  const int n = p >> 1;          // block index, constant per thread
  const int h = p & 1;           // which half of the block I own

  // U rows o = h*4+j, columns permuted: [0..3]=own half, [4..7]=partner half.
  float u[4][8], v[4][8];
  #pragma unroll
  for (int j = 0; j < 4; ++j) {
    const float* urow = Urg + n * 64 + (h * 4 + j) * 8;
    const float* vrow = Uig + n * 64 + (h * 4 + j) * 8;
    float4 uo = *(const float4*)(urow + h * 4);
    float4 up = *(const float4*)(urow + (h ^ 1) * 4);
    float4 vo = *(const float4*)(vrow + h * 4);
    float4 vp = *(const float4*)(vrow + (h ^ 1) * 4);
    u[j][0] = uo.x; u[j][1] = uo.y; u[j][2] = uo.z; u[j][3] = uo.w;
    u[j][4] = up.x; u[j][5] = up.y; u[j][6] = up.z; u[j][7] = up.w;
    v[j][0] = vo.x; v[j][1] = vo.y; v[j][2] = vo.z; v[j][3] = vo.w;
    v[j][4] = vp.x; v[j][5] = vp.y; v[j][6] = vp.z; v[j][7] = vp.w;
  }
  // Pin U in VGPRs (R1 failure mode: compiler sinks U loads into the loop).
  #pragma unroll
  for (int j = 0; j < 4; ++j)
    #pragma unroll
    for (int c = 0; c < 8; ++c)
      asm volatile("" : "+v"(u[j][c]), "+v"(v[j][c]));

  const float4* pxr = (const float4*)xr + G;
  const float4* pxi = (const float4*)xi + G;
  floatx4* qor = (floatx4*)out + G;
  floatx4* qoi = (floatx4*)(out + PLANE) + G;

  #pragma unroll 2
  for (int k = 0; k < NITER; ++k) {
    float4 a = *pxr;                       // my half of the block (xr)
    float4 b = *pxi;                       // my half of the block (xi)
    float oxr[4] = {a.x, a.y, a.z, a.w};
    float oxi[4] = {b.x, b.y, b.z, b.w};
    float pxr_[4], pxi_[4];
    #pragma unroll
    for (int c = 0; c < 4; ++c) {
      pxr_[c] = __shfl_xor(oxr[c], 1, 64); // partner half (xr)
      pxi_[c] = __shfl_xor(oxi[c], 1, 64); // partner half (xi)
    }

    floatx4 sr, si;
    #pragma unroll
    for (int j = 0; j < 4; ++j) {
      float r0 = u[j][0] * oxr[0];
      float i0 = u[j][0] * oxi[0];
      #pragma unroll
      for (int c = 1; c < 4; ++c) {
        r0 = fmaf(u[j][c], oxr[c], r0);
        i0 = fmaf(u[j][c], oxi[c], i0);
      }
      #pragma unroll
      for (int c = 0; c < 4; ++c) {
        r0 = fmaf(u[j][4 + c], pxr_[c], r0);
        i0 = fmaf(u[j][4 + c], pxi_[c], i0);
      }
      #pragma unroll
      for (int c = 0; c < 4; ++c) {
        r0 = fmaf(-v[j][c], oxi[c], r0);
        i0 = fmaf(v[j][c], oxr[c], i0);
      }
      #pragma unroll
      for (int c = 0; c < 4; ++c) {
        r0 = fmaf(-v[j][4 + c], pxi_[c], r0);
        i0 = fmaf(v[j][4 + c], pxr_[c], i0);
      }
      sr[j] = r0;
      si[j] = i0;
    }

    __builtin_nontemporal_store(sr, qor);
    __builtin_nontemporal_store(si, qoi);

    pxr += THREADS; pxi += THREADS; qor += THREADS; qoi += THREADS;
  }
}

extern "C" void kernel_launch(void* const* d_in, const int* in_sizes, int n_in,
                              void* d_out, int out_size, void* d_ws, size_t ws_size,
                              hipStream_t stream) {
  const float* xr = (const float*)d_in[0];
  const float* xi = (const float*)d_in[1];
  const float* Ar = (const float*)d_in[2];
  const float* Ai = (const float*)d_in[3];
  float* out = (float*)d_out;

  float* Ur = (float*)d_ws;              // 128*64 floats = 32 KB
  float* Ui = Ur + NBLK * 64;            // next 32 KB

  cayley_kernel<<<8, 256, 0, stream>>>(Ar, Ai, Ur, Ui);
  apply_kernel<<<APPLY_WGS, 256, 0, stream>>>(xr, xi, Ur, Ui, out);
}

// Round 7
// 69.295 us; speedup vs baseline: 7.2326x; 7.2326x over previous
//
#include <hip/hip_runtime.h>

#define NBLK 128
#define BLK  8
#define BB   4
#define SS   4096
#define DD   1024
#define PLANE (BB * SS * DD)          // 16,777,216 floats per output plane
#define APPLY_WGS 4096
#define THREADS (APPLY_WGS * 256)     // 1,048,576 threads
#define NITER (PLANE / 4 / THREADS)   // 4 float4-tiles per thread

typedef float floatx4 __attribute__((ext_vector_type(4)));

// ---------------------------------------------------------------------------
// Kernel 1: Cayley transform. 128 independent 16x16 solves (real-block
// isomorphism of the 8x8 complex system). 16 threads per solve, one row
// each; row kept in registers; pivot row broadcast through LDS.
// ---------------------------------------------------------------------------
__global__ __launch_bounds__(256) void cayley_kernel(
    const float* __restrict__ Ar, const float* __restrict__ Ai,
    float* __restrict__ Ur, float* __restrict__ Ui) {
  __shared__ float piv[16][33];
  const int s = threadIdx.x >> 4;
  const int r = threadIdx.x & 15;
  const int n = blockIdx.x * 16 + s;
  const float* arb = Ar + n * 64;
  const float* aib = Ai + n * 64;

  float row[32];
  if (r < 8) {
    #pragma unroll
    for (int c = 0; c < 8; ++c) {
      float sk = 0.5f * (arb[r * 8 + c] - arb[c * 8 + r]);
      float sy = 0.5f * (aib[r * 8 + c] + aib[c * 8 + r]);
      float d  = (c == r) ? 1.0f : 0.0f;
      row[c]      = d + sk;
      row[8 + c]  = -sy;
      row[16 + c] = d - sk;
      row[24 + c] = sy;
    }
  } else {
    const int rr = r - 8;
    #pragma unroll
    for (int c = 0; c < 8; ++c) {
      float sk = 0.5f * (arb[rr * 8 + c] - arb[c * 8 + rr]);
      float sy = 0.5f * (aib[rr * 8 + c] + aib[c * 8 + rr]);
      float d  = (c == rr) ? 1.0f : 0.0f;
      row[c]      = sy;
      row[8 + c]  = d + sk;
      row[16 + c] = -sy;
      row[24 + c] = d - sk;
    }
  }

  #pragma unroll
  for (int k = 0; k < 16; ++k) {
    if (r == k) {
      float inv = 1.0f / row[k];
      #pragma unroll
      for (int j = 0; j < 32; ++j) { row[j] *= inv; piv[s][j] = row[j]; }
    }
    __syncthreads();
    if (r != k) {
      float f = row[k];
      #pragma unroll
      for (int j = 0; j < 32; ++j) row[j] = fmaf(-f, piv[s][j], row[j]);
    }
    __syncthreads();
  }

  if (r < 8) {
    #pragma unroll
    for (int c = 0; c < 8; ++c) Ur[n * 64 + r * 8 + c] = row[16 + c];
  } else {
    #pragma unroll
    for (int c = 0; c < 8; ++c) Ui[n * 64 + (r - 8) * 8 + c] = row[16 + c];
  }
}

// ---------------------------------------------------------------------------
// Kernel 2 (R7 = R5 body + 4096 wgs + launch_bounds(256,4)):
//  - R5 proved this body compiles to EXACTLY 64 VGPR under (256,4), and
//    64 VGPR is the 8-waves/SIMD ceiling (512/8). Residency is set by the
//    actual VGPR count, so the hint stays at 4 while HW hosts 8 wg/CU.
//  - R6 lesson: (256,8) forced VGPR=32 -> 64 pinned floats spilled ->
//    1.96 GB scratch traffic/dispatch, 6.7x slowdown. Never again.
//  - R5 lesson: 1024 wgs capped residency at 4 wg/CU; 4096 wgs removes
//    the grid cap (CU cycles through 2 resident batches of 8).
//  - Body: one float4 (half block, 4 output rows) per thread; dense
//    16B/lane loads; partner half via __shfl_xor(.,1); U pinned in VGPRs;
//    float4 non-temporal stores.
// ---------------------------------------------------------------------------
__global__ __launch_bounds__(256, 4) void apply_kernel(
    const float* __restrict__ xr, const float* __restrict__ xi,
    const float* __restrict__ Urg, const float* __restrict__ Uig,
    float* __restrict__ out) {
  const int G = blockIdx.x * 256 + threadIdx.x;   // thread linear id
  const int p = G & 255;         // position within 256-float4 (=1024-elem) tile
  const int n = p >> 1;          // block index, constant per thread
  const int h = p & 1;           // which half of the block I own

  // U rows o = h*4+j, columns permuted: [0..3]=own half, [4..7]=partner half.
  float u[4][8], v[4][8];
  #pragma unroll
  for (int j = 0; j < 4; ++j) {
    const float* urow = Urg + n * 64 + (h * 4 + j) * 8;
    const float* vrow = Uig + n * 64 + (h * 4 + j) * 8;
    float4 uo = *(const float4*)(urow + h * 4);
    float4 up = *(const float4*)(urow + (h ^ 1) * 4);
    float4 vo = *(const float4*)(vrow + h * 4);
    float4 vp = *(const float4*)(vrow + (h ^ 1) * 4);
    u[j][0] = uo.x; u[j][1] = uo.y; u[j][2] = uo.z; u[j][3] = uo.w;
    u[j][4] = up.x; u[j][5] = up.y; u[j][6] = up.z; u[j][7] = up.w;
    v[j][0] = vo.x; v[j][1] = vo.y; v[j][2] = vo.z; v[j][3] = vo.w;
    v[j][4] = vp.x; v[j][5] = vp.y; v[j][6] = vp.z; v[j][7] = vp.w;
  }
  // Pin U in VGPRs (R1 failure mode: compiler sinks U loads into the loop).
  #pragma unroll
  for (int j = 0; j < 4; ++j)
    #pragma unroll
    for (int c = 0; c < 8; ++c)
      asm volatile("" : "+v"(u[j][c]), "+v"(v[j][c]));

  const float4* pxr = (const float4*)xr + G;
  const float4* pxi = (const float4*)xi + G;
  floatx4* qor = (floatx4*)out + G;
  floatx4* qoi = (floatx4*)(out + PLANE) + G;

  #pragma unroll 2
  for (int k = 0; k < NITER; ++k) {
    float4 a = *pxr;                       // my half of the block (xr)
    float4 b = *pxi;                       // my half of the block (xi)
    float oxr[4] = {a.x, a.y, a.z, a.w};
    float oxi[4] = {b.x, b.y, b.z, b.w};
    float pxr_[4], pxi_[4];
    #pragma unroll
    for (int c = 0; c < 4; ++c) {
      pxr_[c] = __shfl_xor(oxr[c], 1, 64); // partner half (xr)
      pxi_[c] = __shfl_xor(oxi[c], 1, 64); // partner half (xi)
    }

    floatx4 sr, si;
    #pragma unroll
    for (int j = 0; j < 4; ++j) {
      float r0 = u[j][0] * oxr[0];
      float i0 = u[j][0] * oxi[0];
      #pragma unroll
      for (int c = 1; c < 4; ++c) {
        r0 = fmaf(u[j][c], oxr[c], r0);
        i0 = fmaf(u[j][c], oxi[c], i0);
      }
      #pragma unroll
      for (int c = 0; c < 4; ++c) {
        r0 = fmaf(u[j][4 + c], pxr_[c], r0);
        i0 = fmaf(u[j][4 + c], pxi_[c], i0);
      }
      #pragma unroll
      for (int c = 0; c < 4; ++c) {
        r0 = fmaf(-v[j][c], oxi[c], r0);
        i0 = fmaf(v[j][c], oxr[c], i0);
      }
      #pragma unroll
      for (int c = 0; c < 4; ++c) {
        r0 = fmaf(-v[j][4 + c], pxi_[c], r0);
        i0 = fmaf(v[j][4 + c], pxr_[c], i0);
      }
      sr[j] = r0;
      si[j] = i0;
    }

    __builtin_nontemporal_store(sr, qor);
    __builtin_nontemporal_store(si, qoi);

    pxr += THREADS; pxi += THREADS; qor += THREADS; qoi += THREADS;
  }
}

extern "C" void kernel_launch(void* const* d_in, const int* in_sizes, int n_in,
                              void* d_out, int out_size, void* d_ws, size_t ws_size,
                              hipStream_t stream) {
  const float* xr = (const float*)d_in[0];
  const float* xi = (const float*)d_in[1];
  const float* Ar = (const float*)d_in[2];
  const float* Ai = (const float*)d_in[3];
  float* out = (float*)d_out;

  float* Ur = (float*)d_ws;              // 128*64 floats = 32 KB
  float* Ui = Ur + NBLK * 64;            // next 32 KB

  cayley_kernel<<<8, 256, 0, stream>>>(Ar, Ai, Ur, Ui);
  apply_kernel<<<APPLY_WGS, 256, 0, stream>>>(xr, xi, Ur, Ui, out);
}

// Round 8
// 60.399 us; speedup vs baseline: 8.2980x; 1.1473x over previous
//
#include <hip/hip_runtime.h>

#define NBLK 128
#define BLK  8
#define BB   4
#define SS   4096
#define DD   1024
#define PLANE (BB * SS * DD)          // 16,777,216 floats per output plane
#define APPLY_WGS 1024
#define THREADS (APPLY_WGS * 256)     // 262,144 threads
#define NITER (PLANE / 4 / THREADS)   // 16 float4-tiles per thread

typedef float floatx4 __attribute__((ext_vector_type(4)));

// ---------------------------------------------------------------------------
// Kernel 1: Cayley transform. 128 independent 16x16 solves. R8: 64-thread
// workgroups (1 wave) x 32 wgs — barriers are intra-wave (nearly free), 32
// CUs busy instead of 8, lower serial latency before apply can start.
// ---------------------------------------------------------------------------
__global__ __launch_bounds__(64) void cayley_kernel(
    const float* __restrict__ Ar, const float* __restrict__ Ai,
    float* __restrict__ Ur, float* __restrict__ Ui) {
  __shared__ float piv[4][33];
  const int s = threadIdx.x >> 4;        // solve slot (0..3)
  const int r = threadIdx.x & 15;        // my row of the 16x32 augmented mat
  const int n = blockIdx.x * 4 + s;      // block index 0..127
  const float* arb = Ar + n * 64;
  const float* aib = Ai + n * 64;

  float row[32];
  if (r < 8) {
    #pragma unroll
    for (int c = 0; c < 8; ++c) {
      float sk = 0.5f * (arb[r * 8 + c] - arb[c * 8 + r]);
      float sy = 0.5f * (aib[r * 8 + c] + aib[c * 8 + r]);
      float d  = (c == r) ? 1.0f : 0.0f;
      row[c]      = d + sk;
      row[8 + c]  = -sy;
      row[16 + c] = d - sk;
      row[24 + c] = sy;
    }
  } else {
    const int rr = r - 8;
    #pragma unroll
    for (int c = 0; c < 8; ++c) {
      float sk = 0.5f * (arb[rr * 8 + c] - arb[c * 8 + rr]);
      float sy = 0.5f * (aib[rr * 8 + c] + aib[c * 8 + rr]);
      float d  = (c == rr) ? 1.0f : 0.0f;
      row[c]      = sy;
      row[8 + c]  = d + sk;
      row[16 + c] = -sy;
      row[24 + c] = d - sk;
    }
  }

  #pragma unroll
  for (int k = 0; k < 16; ++k) {
    if (r == k) {
      float inv = 1.0f / row[k];
      #pragma unroll
      for (int j = 0; j < 32; ++j) { row[j] *= inv; piv[s][j] = row[j]; }
    }
    __syncthreads();
    if (r != k) {
      float f = row[k];
      #pragma unroll
      for (int j = 0; j < 32; ++j) row[j] = fmaf(-f, piv[s][j], row[j]);
    }
    __syncthreads();
  }

  if (r < 8) {
    #pragma unroll
    for (int c = 0; c < 8; ++c) Ur[n * 64 + r * 8 + c] = row[16 + c];
  } else {
    #pragma unroll
    for (int c = 0; c < 8; ++c) Ui[n * 64 + (r - 8) * 8 + c] = row[16 + c];
  }
}

// ---------------------------------------------------------------------------
// Kernel 2 (R8 = R5 minus shfl): one float4 (half block, 4 output rows) per
// thread, U rows pinned in VGPRs, dense loads, float4 NT stores.
// CHANGE vs R5: partner half is a DIRECT global load (idx^1) instead of
// 8x __shfl_xor. The shfl was an LDS round-trip coupled into every
// iteration's critical path (load -> vmcnt wait -> ds_bpermute -> lgkm wait
// -> FMA). Now each iter is {4 independent loads -> FMA -> store}; partner
// lanes hit the same L1 lines (coalescer merges). Zero LDS ops in apply.
// Grid back to 1024 wgs / NITER=16 (R7 showed 4096 wgs only multiplies the
// per-wg U-setup cost; occupancy is VGPR-capped at 16 waves/CU either way).
// ---------------------------------------------------------------------------
__global__ __launch_bounds__(256, 4) void apply_kernel(
    const float* __restrict__ xr, const float* __restrict__ xi,
    const float* __restrict__ Urg, const float* __restrict__ Uig,
    float* __restrict__ out) {
  const int G = blockIdx.x * 256 + threadIdx.x;   // thread linear id
  const int p = G & 255;         // position within 256-float4 (=1024-elem) tile
  const int n = p >> 1;          // block index, constant per thread
  const int h = p & 1;           // which half of the block I own

  // U rows o = h*4+j, columns permuted: [0..3]=own half, [4..7]=partner half.
  float u[4][8], v[4][8];
  #pragma unroll
  for (int j = 0; j < 4; ++j) {
    const float* urow = Urg + n * 64 + (h * 4 + j) * 8;
    const float* vrow = Uig + n * 64 + (h * 4 + j) * 8;
    float4 uo = *(const float4*)(urow + h * 4);
    float4 up = *(const float4*)(urow + (h ^ 1) * 4);
    float4 vo = *(const float4*)(vrow + h * 4);
    float4 vp = *(const float4*)(vrow + (h ^ 1) * 4);
    u[j][0] = uo.x; u[j][1] = uo.y; u[j][2] = uo.z; u[j][3] = uo.w;
    u[j][4] = up.x; u[j][5] = up.y; u[j][6] = up.z; u[j][7] = up.w;
    v[j][0] = vo.x; v[j][1] = vo.y; v[j][2] = vo.z; v[j][3] = vo.w;
    v[j][4] = vp.x; v[j][5] = vp.y; v[j][6] = vp.z; v[j][7] = vp.w;
  }
  // Pin U in VGPRs (R1 failure mode: compiler sinks U loads into the loop).
  #pragma unroll
  for (int j = 0; j < 4; ++j)
    #pragma unroll
    for (int c = 0; c < 8; ++c)
      asm volatile("" : "+v"(u[j][c]), "+v"(v[j][c]));

  const float4* pxr = (const float4*)xr;
  const float4* pxi = (const float4*)xi;
  floatx4* qor = (floatx4*)out;
  floatx4* qoi = (floatx4*)(out + PLANE);

  #pragma unroll 2
  for (int k = 0; k < NITER; ++k) {
    const int idx = k * THREADS + G;     // dense float4 index; partner = idx^1
    float4 a  = pxr[idx];                // own half, xr
    float4 ap = pxr[idx ^ 1];            // partner half, xr (same L1 lines)
    float4 b  = pxi[idx];                // own half, xi
    float4 bp = pxi[idx ^ 1];            // partner half, xi

    float oxr[4] = {a.x, a.y, a.z, a.w};
    float oxi[4] = {b.x, b.y, b.z, b.w};
    float wxr[4] = {ap.x, ap.y, ap.z, ap.w};
    float wxi[4] = {bp.x, bp.y, bp.z, bp.w};

    floatx4 sr, si;
    #pragma unroll
    for (int j = 0; j < 4; ++j) {
      float r0 = u[j][0] * oxr[0];
      float i0 = u[j][0] * oxi[0];
      #pragma unroll
      for (int c = 1; c < 4; ++c) {
        r0 = fmaf(u[j][c], oxr[c], r0);
        i0 = fmaf(u[j][c], oxi[c], i0);
      }
      #pragma unroll
      for (int c = 0; c < 4; ++c) {
        r0 = fmaf(u[j][4 + c], wxr[c], r0);
        i0 = fmaf(u[j][4 + c], wxi[c], i0);
      }
      #pragma unroll
      for (int c = 0; c < 4; ++c) {
        r0 = fmaf(-v[j][c], oxi[c], r0);
        i0 = fmaf(v[j][c], oxr[c], i0);
      }
      #pragma unroll
      for (int c = 0; c < 4; ++c) {
        r0 = fmaf(-v[j][4 + c], wxi[c], r0);
        i0 = fmaf(v[j][4 + c], wxr[c], i0);
      }
      sr[j] = r0;
      si[j] = i0;
    }

    __builtin_nontemporal_store(sr, qor + idx);
    __builtin_nontemporal_store(si, qoi + idx);
  }
}

extern "C" void kernel_launch(void* const* d_in, const int* in_sizes, int n_in,
                              void* d_out, int out_size, void* d_ws, size_t ws_size,
                              hipStream_t stream) {
  const float* xr = (const float*)d_in[0];
  const float* xi = (const float*)d_in[1];
  const float* Ar = (const float*)d_in[2];
  const float* Ai = (const float*)d_in[3];
  float* out = (float*)d_out;

  float* Ur = (float*)d_ws;              // 128*64 floats = 32 KB
  float* Ui = Ur + NBLK * 64;            // next 32 KB

  cayley_kernel<<<32, 64, 0, stream>>>(Ar, Ai, Ur, Ui);
  apply_kernel<<<APPLY_WGS, 256, 0, stream>>>(xr, xi, Ur, Ui, out);
}

// Round 9
// 58.289 us; speedup vs baseline: 8.5983x; 1.0362x over previous
//
#include <hip/hip_runtime.h>

#define NBLK 128
#define BLK  8
#define BB   4
#define SS   4096
#define DD   1024
#define PLANE (BB * SS * DD)          // 16,777,216 floats per output plane
#define APPLY_WGS 1024
#define THREADS (APPLY_WGS * 256)     // 262,144 threads
#define NITER (PLANE / 4 / THREADS)   // 16 float4-tiles per thread

typedef float floatx4 __attribute__((ext_vector_type(4)));

// ---------------------------------------------------------------------------
// Kernel 1: Cayley transform. 128 independent 16x16 solves. 64-thread
// workgroups (1 wave) x 32 wgs — intra-wave barriers, 32 CUs busy.
// ---------------------------------------------------------------------------
__global__ __launch_bounds__(64) void cayley_kernel(
    const float* __restrict__ Ar, const float* __restrict__ Ai,
    float* __restrict__ Ur, float* __restrict__ Ui) {
  __shared__ float piv[4][33];
  const int s = threadIdx.x >> 4;        // solve slot (0..3)
  const int r = threadIdx.x & 15;        // my row of the 16x32 augmented mat
  const int n = blockIdx.x * 4 + s;      // block index 0..127
  const float* arb = Ar + n * 64;
  const float* aib = Ai + n * 64;

  float row[32];
  if (r < 8) {
    #pragma unroll
    for (int c = 0; c < 8; ++c) {
      float sk = 0.5f * (arb[r * 8 + c] - arb[c * 8 + r]);
      float sy = 0.5f * (aib[r * 8 + c] + aib[c * 8 + r]);
      float d  = (c == r) ? 1.0f : 0.0f;
      row[c]      = d + sk;
      row[8 + c]  = -sy;
      row[16 + c] = d - sk;
      row[24 + c] = sy;
    }
  } else {
    const int rr = r - 8;
    #pragma unroll
    for (int c = 0; c < 8; ++c) {
      float sk = 0.5f * (arb[rr * 8 + c] - arb[c * 8 + rr]);
      float sy = 0.5f * (aib[rr * 8 + c] + aib[c * 8 + rr]);
      float d  = (c == rr) ? 1.0f : 0.0f;
      row[c]      = sy;
      row[8 + c]  = d + sk;
      row[16 + c] = -sy;
      row[24 + c] = d - sk;
    }
  }

  #pragma unroll
  for (int k = 0; k < 16; ++k) {
    if (r == k) {
      float inv = 1.0f / row[k];
      #pragma unroll
      for (int j = 0; j < 32; ++j) { row[j] *= inv; piv[s][j] = row[j]; }
    }
    __syncthreads();
    if (r != k) {
      float f = row[k];
      #pragma unroll
      for (int j = 0; j < 32; ++j) row[j] = fmaf(-f, piv[s][j], row[j]);
    }
    __syncthreads();
  }

  if (r < 8) {
    #pragma unroll
    for (int c = 0; c < 8; ++c) Ur[n * 64 + r * 8 + c] = row[16 + c];
  } else {
    #pragma unroll
    for (int c = 0; c < 8; ++c) Ui[n * 64 + (r - 8) * 8 + c] = row[16 + c];
  }
}

// ---------------------------------------------------------------------------
// Kernel 2 (R9 = R8 body, stores via inline-asm "sc0 sc1 nt"):
// R3/R5/R8 all land at ~60us wall across wildly different occupancies ->
// memory-system floor. FETCH=66MB persists: __builtin_nontemporal_store
// still ALLOCATES in MALL (L3), so 128MB of out evicts half of x each
// replay. Probe: system-scope non-temporal stores (sc0 sc1 nt) — if they
// bypass MALL allocation, x stays L3-resident: FETCH -> ~0, HBM ~134MB.
// Explicit vmcnt(0) before kernel end (compiler can't track asm stores).
// ---------------------------------------------------------------------------
__global__ __launch_bounds__(256, 4) void apply_kernel(
    const float* __restrict__ xr, const float* __restrict__ xi,
    const float* __restrict__ Urg, const float* __restrict__ Uig,
    float* __restrict__ out) {
  const int G = blockIdx.x * 256 + threadIdx.x;   // thread linear id
  const int p = G & 255;         // position within 256-float4 (=1024-elem) tile
  const int n = p >> 1;          // block index, constant per thread
  const int h = p & 1;           // which half of the block I own

  // U rows o = h*4+j, columns permuted: [0..3]=own half, [4..7]=partner half.
  float u[4][8], v[4][8];
  #pragma unroll
  for (int j = 0; j < 4; ++j) {
    const float* urow = Urg + n * 64 + (h * 4 + j) * 8;
    const float* vrow = Uig + n * 64 + (h * 4 + j) * 8;
    float4 uo = *(const float4*)(urow + h * 4);
    float4 up = *(const float4*)(urow + (h ^ 1) * 4);
    float4 vo = *(const float4*)(vrow + h * 4);
    float4 vp = *(const float4*)(vrow + (h ^ 1) * 4);
    u[j][0] = uo.x; u[j][1] = uo.y; u[j][2] = uo.z; u[j][3] = uo.w;
    u[j][4] = up.x; u[j][5] = up.y; u[j][6] = up.z; u[j][7] = up.w;
    v[j][0] = vo.x; v[j][1] = vo.y; v[j][2] = vo.z; v[j][3] = vo.w;
    v[j][4] = vp.x; v[j][5] = vp.y; v[j][6] = vp.z; v[j][7] = vp.w;
  }
  // Pin U in VGPRs (R1 failure mode: compiler sinks U loads into the loop).
  #pragma unroll
  for (int j = 0; j < 4; ++j)
    #pragma unroll
    for (int c = 0; c < 8; ++c)
      asm volatile("" : "+v"(u[j][c]), "+v"(v[j][c]));

  const float4* pxr = (const float4*)xr;
  const float4* pxi = (const float4*)xi;
  floatx4* qor = (floatx4*)out;
  floatx4* qoi = (floatx4*)(out + PLANE);

  #pragma unroll 2
  for (int k = 0; k < NITER; ++k) {
    const int idx = k * THREADS + G;     // dense float4 index; partner = idx^1
    float4 a  = pxr[idx];                // own half, xr
    float4 ap = pxr[idx ^ 1];            // partner half, xr (same L1 lines)
    float4 b  = pxi[idx];                // own half, xi
    float4 bp = pxi[idx ^ 1];            // partner half, xi

    float oxr[4] = {a.x, a.y, a.z, a.w};
    float oxi[4] = {b.x, b.y, b.z, b.w};
    float wxr[4] = {ap.x, ap.y, ap.z, ap.w};
    float wxi[4] = {bp.x, bp.y, bp.z, bp.w};

    floatx4 sr, si;
    #pragma unroll
    for (int j = 0; j < 4; ++j) {
      float r0 = u[j][0] * oxr[0];
      float i0 = u[j][0] * oxi[0];
      #pragma unroll
      for (int c = 1; c < 4; ++c) {
        r0 = fmaf(u[j][c], oxr[c], r0);
        i0 = fmaf(u[j][c], oxi[c], i0);
      }
      #pragma unroll
      for (int c = 0; c < 4; ++c) {
        r0 = fmaf(u[j][4 + c], wxr[c], r0);
        i0 = fmaf(u[j][4 + c], wxi[c], i0);
      }
      #pragma unroll
      for (int c = 0; c < 4; ++c) {
        r0 = fmaf(-v[j][c], oxi[c], r0);
        i0 = fmaf(v[j][c], oxr[c], i0);
      }
      #pragma unroll
      for (int c = 0; c < 4; ++c) {
        r0 = fmaf(-v[j][4 + c], wxi[c], r0);
        i0 = fmaf(v[j][4 + c], wxr[c], i0);
      }
      sr[j] = r0;
      si[j] = i0;
    }

    // System-scope non-temporal stores: probe MALL (L3) no-allocate.
    asm volatile("global_store_dwordx4 %0, %1, off sc0 sc1 nt"
                 :: "v"(qor + idx), "v"(sr) : "memory");
    asm volatile("global_store_dwordx4 %0, %1, off sc0 sc1 nt"
                 :: "v"(qoi + idx), "v"(si) : "memory");
  }

  // Compiler can't see the asm stores in its vmcnt bookkeeping; drain before
  // the wave exits so all writes are in flight-complete at dispatch end.
  asm volatile("s_waitcnt vmcnt(0)" ::: "memory");
}

extern "C" void kernel_launch(void* const* d_in, const int* in_sizes, int n_in,
                              void* d_out, int out_size, void* d_ws, size_t ws_size,
                              hipStream_t stream) {
  const float* xr = (const float*)d_in[0];
  const float* xi = (const float*)d_in[1];
  const float* Ar = (const float*)d_in[2];
  const float* Ai = (const float*)d_in[3];
  float* out = (float*)d_out;

  float* Ur = (float*)d_ws;              // 128*64 floats = 32 KB
  float* Ui = Ur + NBLK * 64;            // next 32 KB

  cayley_kernel<<<32, 64, 0, stream>>>(Ar, Ai, Ur, Ui);
  apply_kernel<<<APPLY_WGS, 256, 0, stream>>>(xr, xi, Ur, Ui, out);
}